// Round 14
// baseline (316.883 us; speedup 1.0000x reference)
//
#include <hip/hip_runtime.h>

#define NODES   50000
#define EDGES   800000
#define GRAPHS  500
#define HID     128
#define OUTC    10
#define NLAYERS 3
#define ELLCAP  64
#define NTILES  1563                            // ceil(NODES/32)

typedef __bf16 bf16x8 __attribute__((ext_vector_type(8)));
typedef float  f32x4  __attribute__((ext_vector_type(4)));

__device__ __forceinline__ unsigned short f2bf(float f){
    unsigned u = __float_as_uint(f);
    u = (u + 0x7fffu + ((u >> 16) & 1u)) >> 16;
    return (unsigned short)u;
}
__device__ __forceinline__ float bf2f(unsigned short h){
    return __uint_as_float(((unsigned)h) << 16);
}

#define FILLB  ((EDGES + 255) / 256)            // 3125
#define PREPB  ((6 * HID * HID + 255) / 256)    // 384
#define CONVB  ((NODES * 64 + 255) / 256)       // 12500

// ---------------------------------------------------------------------------
// Fused setup: transposed-ELL fill | weight transpose+bf16 | x->bf16 SPLIT.
// Feature layout everywhere: [half][NODES][64] bf16 -- a neighbor half-row is
// ONE 128B line (halves the random-line count vs 256B rows).
// ---------------------------------------------------------------------------
__global__ __launch_bounds__(256) void setup_kernel(
    const int* __restrict__ src, const int* __restrict__ dst,
    int* __restrict__ deg, unsigned short* __restrict__ ell,
    const float* __restrict__ w1, const float* __restrict__ w2,
    unsigned short* __restrict__ wt,
    const float* __restrict__ x, unsigned* __restrict__ xb)
{
    const int b = blockIdx.x;
    if (b < FILLB) {
        int e = b * 256 + threadIdx.x;
        if (e < EDGES) {
            int d = dst[e];
            int pos = atomicAdd(&deg[d], 1);
            if (pos < ELLCAP)
                ell[(size_t)pos * NODES + d] = (unsigned short)src[e];
        }
    } else if (b < FILLB + PREPB) {
        int idx = (b - FILLB) * 256 + threadIdx.x;
        if (idx < 6 * HID * HID) {
            int m = idx >> 14;
            int n = (idx >> 7) & 127;
            int k = idx & 127;
            const float* w = (m < 3) ? (w1 + (size_t)m * HID * HID)
                                     : (w2 + (size_t)(m - 3) * HID * HID);
            wt[idx] = f2bf(w[(size_t)k * HID + n]);
        }
    } else {
        int i = (b - FILLB - PREPB) * 256 + threadIdx.x;   // f32 pair index
        if (i < NODES * 64) {
            float2 v = reinterpret_cast<const float2*>(x)[i];
            int node = i >> 6;
            int pr   = i & 63;
            int hc   = pr >> 5;                            // column half
            xb[((size_t)hc * NODES + node) * 32 + (pr & 31)] =
                ((unsigned)f2bf(v.y) << 16) | f2bf(v.x);
        }
    }
}

// ---------------------------------------------------------------------------
// Gather pass kernel: grid = 2 x NTILES blocks; pass = blockIdx/NTILES so
// blocks of one pass dispatch together -> each XCD L2 works on one 6.4MB
// half-slice of x (hit-rate up). Per pass each neighbor read = ONE 128B line.
// Block: 512 thr (8 waves), 32-node tile; wave w gathers 4 nodes; per node
// 8 neighbor slots x 16B-segment lanes, 16 edges in flight.
// ---------------------------------------------------------------------------
__global__ __launch_bounds__(512) void gather_pass_kernel(
    const unsigned short* __restrict__ X,     // [2][NODES][64]
    const int* __restrict__ deg, const unsigned short* __restrict__ ell,
    unsigned short* __restrict__ hin)         // [2][NODES][64]
{
    __shared__ unsigned short idx_s[ELLCAP][32];
    __shared__ int deg_s[32];
    const int tid  = threadIdx.x;
    const int bid  = blockIdx.x;
    const int pass = bid / NTILES;            // 0 or 1
    const int row0 = (bid - pass * NTILES) * 32;
    const int w    = tid >> 6;
    const int lane = tid & 63;
    const int q8   = lane >> 3;               // neighbor slot 0..7
    const int l8   = lane & 7;                // 16B segment in 128B half-row

    const uint4* xr = reinterpret_cast<const uint4*>(X) + (size_t)pass * NODES * 8;
    uint4*       hr = reinterpret_cast<uint4*>(hin)     + (size_t)pass * NODES * 8;

    if (tid < 32) {
        int n = row0 + tid; if (n >= NODES) n = NODES - 1;
        deg_s[tid] = min(deg[n], ELLCAP);
    }
    __syncthreads();

    int maxd = 0;
    #pragma unroll
    for (int i = 0; i < 32; ++i) maxd = max(maxd, deg_s[i]);

    {
        const int sl0 = tid >> 5, nn = tid & 31;
        int gn = row0 + nn; if (gn >= NODES) gn = NODES - 1;
        for (int s = sl0; s < maxd; s += 16)
            idx_s[s][nn] = ell[(size_t)s * NODES + gn];
    }
    __syncthreads();

    for (int i = 0; i < 4; ++i) {
        const int row = w * 4 + i;
        int n = row0 + row; if (n >= NODES) n = NODES - 1;

        float acc[8];
        #pragma unroll
        for (int k = 0; k < 8; ++k) acc[k] = 0.f;

        const int dg = deg_s[row];
        for (int e0 = 0; e0 < dg; e0 += 16) {
            uint4 v[2]; unsigned m[2];
            #pragma unroll
            for (int j = 0; j < 2; ++j) {
                int e = e0 + j * 8 + q8;
                bool ok = e < dg;
                m[j] = ok ? 0xffffffffu : 0u;
                int ec = ok ? e : 0;              // slot 0 always staged; masked
                int s = idx_s[ec][row];
                v[j] = xr[(size_t)s * 8 + l8];
            }
            #pragma unroll
            for (int j = 0; j < 2; ++j) {
                const unsigned uu[4] = {v[j].x, v[j].y, v[j].z, v[j].w};
                #pragma unroll
                for (int k2 = 0; k2 < 4; ++k2) {
                    unsigned uv = uu[k2] & m[j];
                    acc[2 * k2]     += __uint_as_float(uv << 16);
                    acc[2 * k2 + 1] += __uint_as_float(uv & 0xffff0000u);
                }
            }
        }

        #pragma unroll
        for (int k = 0; k < 8; ++k) {
            acc[k] += __shfl_xor(acc[k], 8, 64);
            acc[k] += __shfl_xor(acc[k], 16, 64);
            acc[k] += __shfl_xor(acc[k], 32, 64);
        }

        if (q8 == 0) {
            uint4 self = xr[(size_t)n * 8 + l8];
            const unsigned su[4] = {self.x, self.y, self.z, self.w};
            uint4 o; unsigned* ou = &o.x;
            #pragma unroll
            for (int jj = 0; jj < 4; ++jj) {
                float c0 = acc[2 * jj]     + __uint_as_float(su[jj] << 16);
                float c1 = acc[2 * jj + 1] + __uint_as_float(su[jj] & 0xffff0000u);
                ou[jj] = ((unsigned)f2bf(c1) << 16) | f2bf(c0);
            }
            hr[(size_t)n * 8 + l8] = o;
        }
    }
}

// ---------------------------------------------------------------------------
// Dual MFMA GEMM, 32-row tile, 512 threads (8 waves), split-layout IO:
//   wave w: row-group (w>>2)*16 x col-quarter (w&3)*32 of
//   C = relu( relu(A@W1+b1) @ W2 + b2 )
// Barrier between GEMM1 A-frag loads and h1 write-back (rows shared by 4
// waves -- round-10 race).
// ---------------------------------------------------------------------------
__global__ __launch_bounds__(512) void gemm_dual_kernel(
    const unsigned short* __restrict__ A,     // [2][NODES][64]
    const unsigned short* __restrict__ Wt1, const float* __restrict__ bias1,
    const unsigned short* __restrict__ Wt2, const float* __restrict__ bias2,
    unsigned short* __restrict__ C)           // [2][NODES][64]
{
    __shared__ unsigned short As[32][136];
    const int tid  = threadIdx.x;
    const int w    = tid >> 6;
    const int lane = tid & 63;
    const int q    = lane >> 4;
    const int lr   = lane & 15;
    const int row0 = blockIdx.x * 32;

    // stage 32 rows (each = two 128B halves) -- 512 chunks of 16B, 1/thread
    {
        int r  = tid >> 4;
        int cw = tid & 15;
        int gr = row0 + r; if (gr >= NODES) gr = NODES - 1;
        int half = cw >> 3;
        uint4 v = reinterpret_cast<const uint4*>(A)[((size_t)half * NODES + gr) * 8 + (cw & 7)];
        *reinterpret_cast<uint4*>(&As[r][cw * 8]) = v;
    }
    __syncthreads();

    const int rg = w >> 2;              // row-group 0..1
    const int cq = w & 3;               // col-quarter 0..3
    const int ar = rg * 16 + lr;

    bf16x8 af[4];
    f32x4 acc[2];

    // ---- GEMM 1 ----
    #pragma unroll
    for (int s = 0; s < 4; ++s)
        af[s] = *reinterpret_cast<const bf16x8*>(&As[ar][s * 32 + q * 8]);
    __syncthreads();   // all waves done READING As before any h1 write-back

    #pragma unroll
    for (int nt = 0; nt < 2; ++nt) acc[nt] = (f32x4){0.f, 0.f, 0.f, 0.f};
    {
        #pragma unroll
        for (int nt = 0; nt < 2; ++nt) {
            const unsigned short* wn = Wt1 + (size_t)(cq * 32 + nt * 16 + lr) * HID + q * 8;
            #pragma unroll
            for (int s = 0; s < 4; ++s) {
                bf16x8 b = *reinterpret_cast<const bf16x8*>(wn + s * 32);
                acc[nt] = __builtin_amdgcn_mfma_f32_16x16x32_bf16(b, af[s], acc[nt], 0, 0, 0);
            }
        }
    }

    // bias1 + relu -> h1 into LDS (own rows x own col-quarter)
    {
        const float4* b4p = reinterpret_cast<const float4*>(bias1);
        #pragma unroll
        for (int nt = 0; nt < 2; ++nt) {
            int col = cq * 32 + nt * 16 + q * 4;
            float4 b4 = b4p[col >> 2];
            ushort4 o;
            o.x = f2bf(fmaxf(acc[nt][0] + b4.x, 0.f));
            o.y = f2bf(fmaxf(acc[nt][1] + b4.y, 0.f));
            o.z = f2bf(fmaxf(acc[nt][2] + b4.z, 0.f));
            o.w = f2bf(fmaxf(acc[nt][3] + b4.w, 0.f));
            *reinterpret_cast<ushort4*>(&As[ar][col]) = o;
        }
    }
    __syncthreads();

    // ---- GEMM 2 ----
    #pragma unroll
    for (int s = 0; s < 4; ++s)
        af[s] = *reinterpret_cast<const bf16x8*>(&As[ar][s * 32 + q * 8]);
    #pragma unroll
    for (int nt = 0; nt < 2; ++nt) acc[nt] = (f32x4){0.f, 0.f, 0.f, 0.f};
    {
        #pragma unroll
        for (int nt = 0; nt < 2; ++nt) {
            const unsigned short* wn = Wt2 + (size_t)(cq * 32 + nt * 16 + lr) * HID + q * 8;
            #pragma unroll
            for (int s = 0; s < 4; ++s) {
                bf16x8 b = *reinterpret_cast<const bf16x8*>(wn + s * 32);
                acc[nt] = __builtin_amdgcn_mfma_f32_16x16x32_bf16(b, af[s], acc[nt], 0, 0, 0);
            }
        }
    }

    const int row = row0 + ar;
    if (row < NODES) {
        const float4* b4p = reinterpret_cast<const float4*>(bias2);
        #pragma unroll
        for (int nt = 0; nt < 2; ++nt) {
            int col = cq * 32 + nt * 16 + q * 4;
            float4 b4 = b4p[col >> 2];
            ushort4 o;
            o.x = f2bf(fmaxf(acc[nt][0] + b4.x, 0.f));
            o.y = f2bf(fmaxf(acc[nt][1] + b4.y, 0.f));
            o.z = f2bf(fmaxf(acc[nt][2] + b4.z, 0.f));
            o.w = f2bf(fmaxf(acc[nt][3] + b4.w, 0.f));
            int half = col >> 6;
            *reinterpret_cast<ushort4*>(
                C + ((size_t)half * NODES + row) * 64 + (col & 63)) = o;
        }
    }
}

// ---------------------------------------------------------------------------
// Pool over sorted batch ids (split bf16 in, f32 out)
// ---------------------------------------------------------------------------
__device__ __forceinline__ int lbound(const int* __restrict__ a, int v)
{
    int lo = 0, hi = NODES;
    while (lo < hi) {
        int m = (lo + hi) >> 1;
        if (a[m] < v) lo = m + 1; else hi = m;
    }
    return lo;
}

__global__ __launch_bounds__(256) void pool_sorted_kernel(
    const unsigned short* __restrict__ x,     // [2][NODES][64]
    const int* __restrict__ batch,
    float* __restrict__ g)
{
    const int gid = blockIdx.x;
    const int beg = lbound(batch, gid);
    const int end = lbound(batch, gid + 1);

    const int c  = threadIdx.x & 127;
    const int hp = threadIdx.x >> 7;          // row parity
    const int ch = c >> 6;                    // column half
    const int co = c & 63;

    float acc = 0.f;
    for (int r = beg + hp; r < end; r += 2)
        acc += bf2f(x[((size_t)ch * NODES + r) * 64 + co]);

    __shared__ float lds[256];
    lds[threadIdx.x] = acc;
    __syncthreads();
    if (threadIdx.x < 128)
        g[(size_t)gid * HID + threadIdx.x] = lds[threadIdx.x] + lds[threadIdx.x + 128];
}

// ---------------------------------------------------------------------------
// Small f32 GEMM for the graph-level MLP (M=500)
// ---------------------------------------------------------------------------
__global__ __launch_bounds__(256) void gemm128_f32_kernel(
    const float* __restrict__ A,
    const float* __restrict__ W,
    const float* __restrict__ bias,
    float* __restrict__ C,
    int M)
{
    __shared__ float As[32][HID];
    const int tid  = threadIdx.x;
    const int row0 = blockIdx.x * 32;

    {
        const int r = tid >> 3;
        const int c = (tid & 7) * 16;
        const int gr = row0 + r;
        float4* ps = reinterpret_cast<float4*>(&As[r][c]);
        if (gr < M) {
            const float4* pa = reinterpret_cast<const float4*>(A + (size_t)gr * HID + c);
            #pragma unroll
            for (int j = 0; j < 4; ++j) ps[j] = pa[j];
        } else {
            #pragma unroll
            for (int j = 0; j < 4; ++j) ps[j] = make_float4(0.f, 0.f, 0.f, 0.f);
        }
    }
    __syncthreads();

    const int tx = tid & 31;
    const int ty = tid >> 5;

    float4 acc[4];
    #pragma unroll
    for (int i = 0; i < 4; ++i) acc[i] = make_float4(0.f, 0.f, 0.f, 0.f);

    #pragma unroll 4
    for (int k = 0; k < HID; ++k) {
        const float4 w = *reinterpret_cast<const float4*>(W + (size_t)k * HID + tx * 4);
        #pragma unroll
        for (int i = 0; i < 4; ++i) {
            const float a = As[ty + 8 * i][k];
            acc[i].x += a * w.x;
            acc[i].y += a * w.y;
            acc[i].z += a * w.z;
            acc[i].w += a * w.w;
        }
    }

    const float4 b4 = *reinterpret_cast<const float4*>(bias + tx * 4);
    #pragma unroll
    for (int i = 0; i < 4; ++i) {
        const int row = row0 + ty + 8 * i;
        if (row < M) {
            float4 o = make_float4(fmaxf(acc[i].x + b4.x, 0.f),
                                   fmaxf(acc[i].y + b4.y, 0.f),
                                   fmaxf(acc[i].z + b4.z, 0.f),
                                   fmaxf(acc[i].w + b4.w, 0.f));
            *reinterpret_cast<float4*>(C + (size_t)row * HID + tx * 4) = o;
        }
    }
}

__global__ __launch_bounds__(256) void final_kernel(
    const float* __restrict__ gh,
    const float* __restrict__ w2,
    const float* __restrict__ b2,
    float* __restrict__ out)
{
    int idx = blockIdx.x * 256 + threadIdx.x;
    int r = idx >> 4;
    int c = idx & 15;
    if (r >= GRAPHS || c >= OUTC) return;
    float acc = b2[c];
    for (int k = 0; k < HID; ++k)
        acc += gh[(size_t)r * HID + k] * w2[(size_t)k * OUTC + c];
    out[(size_t)r * OUTC + c] = acc;
}

// ---------------------------------------------------------------------------
extern "C" void kernel_launch(void* const* d_in, const int* in_sizes, int n_in,
                              void* d_out, int out_size, void* d_ws, size_t ws_size,
                              hipStream_t stream)
{
    const float* x    = (const float*)d_in[0];
    const float* w1   = (const float*)d_in[1];
    const float* b1   = (const float*)d_in[2];
    const float* w2   = (const float*)d_in[3];
    const float* b2   = (const float*)d_in[4];
    const float* mw1  = (const float*)d_in[5];
    const float* mb1  = (const float*)d_in[6];
    const float* mw2  = (const float*)d_in[7];
    const float* mb2  = (const float*)d_in[8];
    const int*   ei   = (const int*)d_in[9];
    const int*   batch= (const int*)d_in[10];
    float* out = (float*)d_out;

    // workspace layout
    char* p = (char*)d_ws;
    unsigned short* buf0 = (unsigned short*)p;  p += (size_t)NODES * HID * 2;
    unsigned short* buf1 = (unsigned short*)p;  p += (size_t)NODES * HID * 2;
    unsigned short* ell  = (unsigned short*)p;  p += (size_t)NODES * ELLCAP * 2;
    unsigned short* wt   = (unsigned short*)p;  p += (size_t)6 * HID * HID * 2;
    float* g      = (float*)p;                  p += (size_t)GRAPHS * HID * 4;
    float* gh     = (float*)p;                  p += (size_t)GRAPHS * HID * 4;
    int*   deg    = (int*)p;                    p += (size_t)NODES * 4;

    const int* src = ei;
    const int* dst = ei + EDGES;

    const int setupBlocks = FILLB + PREPB + CONVB;      // 16009

    // ---- setup: ELL fill + weight prep + x->bf16(split), co-scheduled ----
    hipMemsetAsync(deg, 0, (size_t)NODES * sizeof(int), stream);
    setup_kernel<<<setupBlocks, 256, 0, stream>>>(
        src, dst, deg, ell, w1, w2, wt, x, (unsigned*)buf0);

    // ---- 3 GIN layers: gather(2 ordered passes) + dual GEMM ----
    unsigned short* bin  = buf0;
    unsigned short* bout = buf1;
    for (int l = 0; l < NLAYERS; ++l) {
        gather_pass_kernel<<<2 * NTILES, 512, 0, stream>>>(bin, deg, ell, bout);
        gemm_dual_kernel<<<NTILES, 512, 0, stream>>>(
            bout,
            wt + (size_t)l * HID * HID,       b1 + (size_t)l * HID,
            wt + (size_t)(l + 3) * HID * HID, b2 + (size_t)l * HID,
            bin);
        // bin now holds layer output; keep roles (bin=state, bout=scratch)
    }

    // ---- pool + MLP ----
    pool_sorted_kernel<<<GRAPHS, 256, 0, stream>>>(bin, batch, g);
    gemm128_f32_kernel<<<(GRAPHS + 31) / 32, 256, 0, stream>>>(g, mw1, mb1, gh, GRAPHS);
    final_kernel<<<(GRAPHS * 16 + 255) / 256, 256, 0, stream>>>(gh, mw2, mb2, out);
}

// Round 15
// 252.781 us; speedup vs baseline: 1.2536x; 1.2536x over previous
//
#include <hip/hip_runtime.h>

#define NODES   50000
#define EDGES   800000
#define GRAPHS  500
#define HID     128
#define OUTC    10
#define NLAYERS 3
#define ELLCAP  64

typedef __bf16 bf16x8 __attribute__((ext_vector_type(8)));
typedef float  f32x4  __attribute__((ext_vector_type(4)));

__device__ __forceinline__ unsigned short f2bf(float f){
    unsigned u = __float_as_uint(f);
    u = (u + 0x7fffu + ((u >> 16) & 1u)) >> 16;
    return (unsigned short)u;
}
__device__ __forceinline__ float bf2f(unsigned short h){
    return __uint_as_float(((unsigned)h) << 16);
}

#define FGRPS  8                                // XCD groups
#define FPB    392                              // fill blocks per group
#define FILLB  (FGRPS * FPB)                    // 3136
#define GSZ    (NODES / FGRPS)                  // 6250 nodes per group
#define PREPB  ((6 * HID * HID + 255) / 256)    // 384
#define CONVB  ((NODES * 64 + 255) / 256)       // 12500

// ---------------------------------------------------------------------------
// Fused setup: XCD-partitioned transposed-ELL fill | weight prep | x->bf16.
// Fill: group g (= blockIdx&7, round-robins onto XCDs) scans ALL edges but
// commits only dst in [g*GSZ,(g+1)*GSZ) -> deg/ell lines for a node range
// stay in ONE XCD's L2 (no cross-XCD dirty-line bounce; writebacks = final
// flush only). Edge-list reads are 8x but L3-cached (6.4 MB).
// ---------------------------------------------------------------------------
__global__ __launch_bounds__(256) void setup_kernel(
    const int* __restrict__ src, const int* __restrict__ dst,
    int* __restrict__ deg, unsigned short* __restrict__ ell,
    const float* __restrict__ w1, const float* __restrict__ w2,
    unsigned short* __restrict__ wt,
    const float* __restrict__ x, unsigned* __restrict__ xb)
{
    const int b = blockIdx.x;
    if (b < FILLB) {
        const int grp = b & 7;
        const int bi  = b >> 3;
        const int lo  = grp * GSZ;
        const int hi  = lo + GSZ;
        for (int e = bi * 256 + threadIdx.x; e < EDGES; e += FPB * 256) {
            int d = dst[e];
            if (d >= lo && d < hi) {
                int pos = atomicAdd(&deg[d], 1);
                if (pos < ELLCAP)
                    ell[(size_t)pos * NODES + d] = (unsigned short)src[e];
            }
        }
    } else if (b < FILLB + PREPB) {
        int idx = (b - FILLB) * 256 + threadIdx.x;
        if (idx < 6 * HID * HID) {
            int m = idx >> 14;
            int n = (idx >> 7) & 127;
            int k = idx & 127;
            const float* w = (m < 3) ? (w1 + (size_t)m * HID * HID)
                                     : (w2 + (size_t)(m - 3) * HID * HID);
            wt[idx] = f2bf(w[(size_t)k * HID + n]);
        }
    } else {
        int i = (b - FILLB - PREPB) * 256 + threadIdx.x;   // f32 pair index
        if (i < NODES * 64) {
            float2 v = reinterpret_cast<const float2*>(x)[i];
            xb[i] = ((unsigned)f2bf(v.y) << 16) | f2bf(v.x);
        }
    }
}

// ---------------------------------------------------------------------------
// Fused GIN layer, 32-row tile, 512 threads (8 waves)  [round-12 structure]:
//   phase 0: stage deg[32] + ELL indices into LDS (coalesced, 64B/slot).
//   gather:  wave w gathers rows w*4..w*4+3 (quarter-wave per neighbor,
//            16 edges in flight); indices from LDS (single-hop chain).
//   GEMM:    wave w computes row-group (w>>2)*16 x col-quarter (w&3)*32.
// Barrier between GEMM1 A-frag loads and h1 write-back (rows shared by 4
// waves -- round-10 race).
// ---------------------------------------------------------------------------
__global__ __launch_bounds__(512) void layer_kernel(
    const unsigned short* __restrict__ X,
    const int* __restrict__ deg, const unsigned short* __restrict__ ell,
    const unsigned short* __restrict__ Wt1, const float* __restrict__ bias1,
    const unsigned short* __restrict__ Wt2, const float* __restrict__ bias2,
    unsigned short* __restrict__ C)
{
    __shared__ unsigned short As[32][136];
    __shared__ unsigned short idx_s[ELLCAP][32];   // [slot][node-in-tile], 4 KB
    __shared__ int deg_s[32];
    const int tid  = threadIdx.x;
    const int w    = tid >> 6;          // wave 0..7
    const int lane = tid & 63;
    const int q    = lane >> 4;         // quarter -> neighbor slot / k-chunk
    const int lr   = lane & 15;         // 16B chunk within row / mfma row
    const int row0 = blockIdx.x * 32;

    const uint4* xr = reinterpret_cast<const uint4*>(X);   // 16 uint4 per row

    // ---- phase 0a: stage degrees ----
    if (tid < 32) {
        int n = row0 + tid;
        if (n >= NODES) n = NODES - 1;
        deg_s[tid] = min(deg[n], ELLCAP);
    }
    __syncthreads();

    int maxd = 0;
    #pragma unroll
    for (int i = 0; i < 32; ++i) maxd = max(maxd, deg_s[i]);

    // ---- phase 0b: stage indices, 16 slots per iteration, coalesced ----
    {
        const int sl0 = tid >> 5;          // 0..15
        const int nn  = tid & 31;
        int gn = row0 + nn;
        if (gn >= NODES) gn = NODES - 1;
        for (int s = sl0; s < maxd; s += 16)
            idx_s[s][nn] = ell[(size_t)s * NODES + gn];
    }
    __syncthreads();

    // ---- gather: this wave's 4 rows (single-hop random loads) ----
    for (int i = 0; i < 4; ++i) {
        const int row = w * 4 + i;
        int n = row0 + row;
        if (n >= NODES) n = NODES - 1;      // tail: redundant compute, store guarded

        float acc[8];
        #pragma unroll
        for (int k = 0; k < 8; ++k) acc[k] = 0.f;

        const int dg = deg_s[row];
        for (int e0 = 0; e0 < dg; e0 += 16) {
            uint4 v[4];
            unsigned m[4];
            #pragma unroll
            for (int j = 0; j < 4; ++j) {
                int e = e0 + 4 * j + q;
                bool ok = e < dg;
                m[j] = ok ? 0xffffffffu : 0u;
                int ec = ok ? e : 0;           // slot 0 always staged; masked out
                int s = idx_s[ec][row];
                v[j] = xr[(size_t)s * 16 + lr];
            }
            #pragma unroll
            for (int j = 0; j < 4; ++j) {
                const unsigned uu[4] = {v[j].x, v[j].y, v[j].z, v[j].w};
                #pragma unroll
                for (int k2 = 0; k2 < 4; ++k2) {
                    unsigned uv = uu[k2] & m[j];
                    acc[2 * k2]     += __uint_as_float(uv << 16);
                    acc[2 * k2 + 1] += __uint_as_float(uv & 0xffff0000u);
                }
            }
        }

        #pragma unroll
        for (int k = 0; k < 8; ++k) {
            acc[k] += __shfl_xor(acc[k], 16, 64);
            acc[k] += __shfl_xor(acc[k], 32, 64);
        }

        if (q == 0) {
            uint4 self = xr[(size_t)n * 16 + lr];
            const unsigned su[4] = {self.x, self.y, self.z, self.w};
            uint4 o;
            unsigned* ou = &o.x;
            #pragma unroll
            for (int j = 0; j < 4; ++j) {
                float c0 = acc[2 * j]     + __uint_as_float(su[j] << 16);
                float c1 = acc[2 * j + 1] + __uint_as_float(su[j] & 0xffff0000u);
                ou[j] = ((unsigned)f2bf(c1) << 16) | f2bf(c0);
            }
            *reinterpret_cast<uint4*>(&As[row][lr * 8]) = o;
        }
    }
    __syncthreads();

    const int rg = w >> 2;              // row-group 0..1
    const int cq = w & 3;               // col-quarter 0..3
    const int ar = rg * 16 + lr;        // this wave's mfma row in tile

    bf16x8 af[4];
    f32x4 acc[2];

    // ---- GEMM 1: h1[16 x 32-quarter] ----
    #pragma unroll
    for (int s = 0; s < 4; ++s)
        af[s] = *reinterpret_cast<const bf16x8*>(&As[ar][s * 32 + q * 8]);
    __syncthreads();   // all waves done READING As before any h1 write-back

    #pragma unroll
    for (int nt = 0; nt < 2; ++nt) acc[nt] = (f32x4){0.f, 0.f, 0.f, 0.f};
    {
        #pragma unroll
        for (int nt = 0; nt < 2; ++nt) {
            const unsigned short* wn = Wt1 + (size_t)(cq * 32 + nt * 16 + lr) * HID + q * 8;
            #pragma unroll
            for (int s = 0; s < 4; ++s) {
                bf16x8 b = *reinterpret_cast<const bf16x8*>(wn + s * 32);
                acc[nt] = __builtin_amdgcn_mfma_f32_16x16x32_bf16(b, af[s], acc[nt], 0, 0, 0);
            }
        }
    }

    // bias1 + relu -> h1 into LDS (own rows x own col-quarter)
    {
        const float4* b4p = reinterpret_cast<const float4*>(bias1);
        #pragma unroll
        for (int nt = 0; nt < 2; ++nt) {
            int col = cq * 32 + nt * 16 + q * 4;
            float4 b4 = b4p[col >> 2];
            ushort4 o;
            o.x = f2bf(fmaxf(acc[nt][0] + b4.x, 0.f));
            o.y = f2bf(fmaxf(acc[nt][1] + b4.y, 0.f));
            o.z = f2bf(fmaxf(acc[nt][2] + b4.z, 0.f));
            o.w = f2bf(fmaxf(acc[nt][3] + b4.w, 0.f));
            *reinterpret_cast<ushort4*>(&As[ar][col]) = o;
        }
    }
    __syncthreads();

    // ---- GEMM 2 ----
    #pragma unroll
    for (int s = 0; s < 4; ++s)
        af[s] = *reinterpret_cast<const bf16x8*>(&As[ar][s * 32 + q * 8]);
    #pragma unroll
    for (int nt = 0; nt < 2; ++nt) acc[nt] = (f32x4){0.f, 0.f, 0.f, 0.f};
    {
        #pragma unroll
        for (int nt = 0; nt < 2; ++nt) {
            const unsigned short* wn = Wt2 + (size_t)(cq * 32 + nt * 16 + lr) * HID + q * 8;
            #pragma unroll
            for (int s = 0; s < 4; ++s) {
                bf16x8 b = *reinterpret_cast<const bf16x8*>(wn + s * 32);
                acc[nt] = __builtin_amdgcn_mfma_f32_16x16x32_bf16(b, af[s], acc[nt], 0, 0, 0);
            }
        }
    }

    const int row = row0 + ar;
    if (row < NODES) {
        const float4* b4p = reinterpret_cast<const float4*>(bias2);
        #pragma unroll
        for (int nt = 0; nt < 2; ++nt) {
            int col = cq * 32 + nt * 16 + q * 4;
            float4 b4 = b4p[col >> 2];
            ushort4 o;
            o.x = f2bf(fmaxf(acc[nt][0] + b4.x, 0.f));
            o.y = f2bf(fmaxf(acc[nt][1] + b4.y, 0.f));
            o.z = f2bf(fmaxf(acc[nt][2] + b4.z, 0.f));
            o.w = f2bf(fmaxf(acc[nt][3] + b4.w, 0.f));
            *reinterpret_cast<ushort4*>(C + (size_t)row * HID + col) = o;
        }
    }
}

// ---------------------------------------------------------------------------
// Pool over sorted batch ids (bf16 in, f32 out)
// ---------------------------------------------------------------------------
__device__ __forceinline__ int lbound(const int* __restrict__ a, int v)
{
    int lo = 0, hi = NODES;
    while (lo < hi) {
        int m = (lo + hi) >> 1;
        if (a[m] < v) lo = m + 1; else hi = m;
    }
    return lo;
}

__global__ __launch_bounds__(256) void pool_sorted_kernel(
    const unsigned short* __restrict__ x,
    const int* __restrict__ batch,
    float* __restrict__ g)
{
    const int gid = blockIdx.x;
    const int beg = lbound(batch, gid);
    const int end = lbound(batch, gid + 1);

    const int c    = threadIdx.x & 127;
    const int half = threadIdx.x >> 7;

    float acc = 0.f;
    for (int r = beg + half; r < end; r += 2)
        acc += bf2f(x[(size_t)r * HID + c]);

    __shared__ float lds[256];
    lds[threadIdx.x] = acc;
    __syncthreads();
    if (threadIdx.x < 128)
        g[(size_t)gid * HID + threadIdx.x] = lds[threadIdx.x] + lds[threadIdx.x + 128];
}

// ---------------------------------------------------------------------------
// Small f32 GEMM for the graph-level MLP (M=500)
// ---------------------------------------------------------------------------
__global__ __launch_bounds__(256) void gemm128_f32_kernel(
    const float* __restrict__ A,
    const float* __restrict__ W,
    const float* __restrict__ bias,
    float* __restrict__ C,
    int M)
{
    __shared__ float As[32][HID];
    const int tid  = threadIdx.x;
    const int row0 = blockIdx.x * 32;

    {
        const int r = tid >> 3;
        const int c = (tid & 7) * 16;
        const int gr = row0 + r;
        float4* ps = reinterpret_cast<float4*>(&As[r][c]);
        if (gr < M) {
            const float4* pa = reinterpret_cast<const float4*>(A + (size_t)gr * HID + c);
            #pragma unroll
            for (int j = 0; j < 4; ++j) ps[j] = pa[j];
        } else {
            #pragma unroll
            for (int j = 0; j < 4; ++j) ps[j] = make_float4(0.f, 0.f, 0.f, 0.f);
        }
    }
    __syncthreads();

    const int tx = tid & 31;
    const int ty = tid >> 5;

    float4 acc[4];
    #pragma unroll
    for (int i = 0; i < 4; ++i) acc[i] = make_float4(0.f, 0.f, 0.f, 0.f);

    #pragma unroll 4
    for (int k = 0; k < HID; ++k) {
        const float4 w = *reinterpret_cast<const float4*>(W + (size_t)k * HID + tx * 4);
        #pragma unroll
        for (int i = 0; i < 4; ++i) {
            const float a = As[ty + 8 * i][k];
            acc[i].x += a * w.x;
            acc[i].y += a * w.y;
            acc[i].z += a * w.z;
            acc[i].w += a * w.w;
        }
    }

    const float4 b4 = *reinterpret_cast<const float4*>(bias + tx * 4);
    #pragma unroll
    for (int i = 0; i < 4; ++i) {
        const int row = row0 + ty + 8 * i;
        if (row < M) {
            float4 o = make_float4(fmaxf(acc[i].x + b4.x, 0.f),
                                   fmaxf(acc[i].y + b4.y, 0.f),
                                   fmaxf(acc[i].z + b4.z, 0.f),
                                   fmaxf(acc[i].w + b4.w, 0.f));
            *reinterpret_cast<float4*>(C + (size_t)row * HID + tx * 4) = o;
        }
    }
}

__global__ __launch_bounds__(256) void final_kernel(
    const float* __restrict__ gh,
    const float* __restrict__ w2,
    const float* __restrict__ b2,
    float* __restrict__ out)
{
    int idx = blockIdx.x * 256 + threadIdx.x;
    int r = idx >> 4;
    int c = idx & 15;
    if (r >= GRAPHS || c >= OUTC) return;
    float acc = b2[c];
    for (int k = 0; k < HID; ++k)
        acc += gh[(size_t)r * HID + k] * w2[(size_t)k * OUTC + c];
    out[(size_t)r * OUTC + c] = acc;
}

// ---------------------------------------------------------------------------
extern "C" void kernel_launch(void* const* d_in, const int* in_sizes, int n_in,
                              void* d_out, int out_size, void* d_ws, size_t ws_size,
                              hipStream_t stream)
{
    const float* x    = (const float*)d_in[0];
    const float* w1   = (const float*)d_in[1];
    const float* b1   = (const float*)d_in[2];
    const float* w2   = (const float*)d_in[3];
    const float* b2   = (const float*)d_in[4];
    const float* mw1  = (const float*)d_in[5];
    const float* mb1  = (const float*)d_in[6];
    const float* mw2  = (const float*)d_in[7];
    const float* mb2  = (const float*)d_in[8];
    const int*   ei   = (const int*)d_in[9];
    const int*   batch= (const int*)d_in[10];
    float* out = (float*)d_out;

    // workspace layout
    char* p = (char*)d_ws;
    unsigned short* buf0 = (unsigned short*)p;  p += (size_t)NODES * HID * 2;
    unsigned short* buf1 = (unsigned short*)p;  p += (size_t)NODES * HID * 2;
    unsigned short* ell  = (unsigned short*)p;  p += (size_t)NODES * ELLCAP * 2;
    unsigned short* wt   = (unsigned short*)p;  p += (size_t)6 * HID * HID * 2;
    float* g      = (float*)p;                  p += (size_t)GRAPHS * HID * 4;
    float* gh     = (float*)p;                  p += (size_t)GRAPHS * HID * 4;
    int*   deg    = (int*)p;                    p += (size_t)NODES * 4;

    const int* src = ei;
    const int* dst = ei + EDGES;

    const int layerBlocks = (NODES + 31) / 32;          // 1563
    const int setupBlocks = FILLB + PREPB + CONVB;      // 16020

    // ---- setup: XCD-partitioned ELL fill + weight prep + x->bf16 ----
    hipMemsetAsync(deg, 0, (size_t)NODES * sizeof(int), stream);
    setup_kernel<<<setupBlocks, 256, 0, stream>>>(
        src, dst, deg, ell, w1, w2, wt, x, (unsigned*)buf0);

    // ---- 3 fused GIN layers (gather + dual GEMM), ping-pong buf0/buf1 ----
    unsigned short* bin  = buf0;
    unsigned short* bout = buf1;
    for (int l = 0; l < NLAYERS; ++l) {
        layer_kernel<<<layerBlocks, 512, 0, stream>>>(
            bin, deg, ell,
            wt + (size_t)l * HID * HID,       b1 + (size_t)l * HID,
            wt + (size_t)(l + 3) * HID * HID, b2 + (size_t)l * HID,
            bout);
        unsigned short* t = bin; bin = bout; bout = t;
    }

    // ---- pool + MLP ----
    pool_sorted_kernel<<<GRAPHS, 256, 0, stream>>>(bin, batch, g);
    gemm128_f32_kernel<<<(GRAPHS + 31) / 32, 256, 0, stream>>>(g, mw1, mb1, gh, GRAPHS);
    final_kernel<<<(GRAPHS * 16 + 255) / 256, 256, 0, stream>>>(gh, mw2, mb2, out);
}